// Round 1
// baseline (1140.632 us; speedup 1.0000x reference)
//
#include <hip/hip_runtime.h>
#include <math.h>

#define BLK 256

// ---------------- init: deg=1 (self loop), acc=0, zacc=0 ----------------
__global__ void k_init(int* __restrict__ deg, float* __restrict__ acc,
                       float* __restrict__ zacc, int n, int accn, int ng) {
  int j = blockIdx.x * BLK + threadIdx.x;
  if (j < accn) acc[j] = 0.f;
  if (j < n) deg[j] = 1;
  if (j < ng) zacc[j] = 0.f;
}

// ---------------- degree count over dst ----------------
__global__ void k_deg(const int* __restrict__ dst, int* __restrict__ deg, int E) {
  int i = blockIdx.x * BLK + threadIdx.x;
  if (i < E) atomicAdd(&deg[dst[i]], 1);
}

// ---------------- y1 = dis * (x @ W1); deg buffer becomes dis (in place) ----------------
__global__ void k_y1(const float* __restrict__ x, const float* __restrict__ W1,
                     int* __restrict__ degdis, float* __restrict__ y, int n) {
  __shared__ float sW[128];
  if (threadIdx.x < 128) sW[threadIdx.x] = W1[threadIdx.x];
  __syncthreads();
  int i = blockIdx.x * BLK + threadIdx.x;
  if (i >= n) return;
  const float4* xp = (const float4*)(x + (size_t)i * 16);
  float4 a = xp[0], b = xp[1], c = xp[2], d4 = xp[3];
  float xv[16] = {a.x,a.y,a.z,a.w, b.x,b.y,b.z,b.w,
                  c.x,c.y,c.z,c.w, d4.x,d4.y,d4.z,d4.w};
  float dis = rsqrtf((float)degdis[i]);
  float o[8];
  #pragma unroll
  for (int j = 0; j < 8; ++j) {
    float s = 0.f;
    #pragma unroll
    for (int k = 0; k < 16; ++k) s = fmaf(xv[k], sW[k*8 + j], s);
    o[j] = dis * s;
  }
  ((float*)degdis)[i] = dis;   // overwrite deg with dis (own element only)
  float4* yp = (float4*)(y + (size_t)i * 8);
  yp[0] = make_float4(o[0], o[1], o[2], o[3]);
  yp[1] = make_float4(o[4], o[5], o[6], o[7]);
}

// ---------------- edge scatter: acc[dst][h] += y[src][h] ----------------
__global__ void k_scatter(const int* __restrict__ src, const int* __restrict__ dst,
                          const float* __restrict__ y, float* __restrict__ acc,
                          long long total) {
  long long t = (long long)blockIdx.x * BLK + threadIdx.x;
  if (t >= total) return;
  int e = (int)(t >> 3);
  int h = (int)(t & 7);
  int s = src[e], d = dst[e];
  atomicAdd(&acc[(size_t)d * 8 + h], y[(size_t)s * 8 + h]);
}

// ---------------- h1 = relu(dis*(acc+y)+b1); y <- dis*(h1@W2); acc <- 0 ----------------
__global__ void k_mid(const float* __restrict__ dis, float* __restrict__ y,
                      float* __restrict__ acc, const float* __restrict__ W2,
                      const float* __restrict__ b1, int n) {
  __shared__ float sW[64];
  __shared__ float sb[8];
  if (threadIdx.x < 64) sW[threadIdx.x] = W2[threadIdx.x];
  if (threadIdx.x < 8)  sb[threadIdx.x] = b1[threadIdx.x];
  __syncthreads();
  int i = blockIdx.x * BLK + threadIdx.x;
  if (i >= n) return;
  float d = dis[i];
  float4* yp = (float4*)(y + (size_t)i * 8);
  float4* ap = (float4*)(acc + (size_t)i * 8);
  float4 y0 = yp[0], y1v = yp[1], a0 = ap[0], a1 = ap[1];
  float yy[8] = {y0.x,y0.y,y0.z,y0.w, y1v.x,y1v.y,y1v.z,y1v.w};
  float aa[8] = {a0.x,a0.y,a0.z,a0.w, a1.x,a1.y,a1.z,a1.w};
  float hv[8];
  #pragma unroll
  for (int j = 0; j < 8; ++j) hv[j] = fmaxf(fmaf(d, yy[j] + aa[j], sb[j]), 0.f);
  float o[8];
  #pragma unroll
  for (int j = 0; j < 8; ++j) {
    float s = 0.f;
    #pragma unroll
    for (int k = 0; k < 8; ++k) s = fmaf(hv[k], sW[k*8 + j], s);
    o[j] = d * s;
  }
  yp[0] = make_float4(o[0], o[1], o[2], o[3]);
  yp[1] = make_float4(o[4], o[5], o[6], o[7]);
  ap[0] = make_float4(0.f, 0.f, 0.f, 0.f);
  ap[1] = make_float4(0.f, 0.f, 0.f, 0.f);
}

// ---------------- h2 = relu(dis*(acc+y)+b2); zacc[batch[i]] += h2 . Wl ----------------
__global__ void k_final(const float* __restrict__ dis, const float* __restrict__ y,
                        const float* __restrict__ acc, const float* __restrict__ b2,
                        const float* __restrict__ Wl, const int* __restrict__ batch,
                        float* __restrict__ zacc, int n) {
  __shared__ float sb[8], sw[8];
  if (threadIdx.x < 8) { sb[threadIdx.x] = b2[threadIdx.x]; sw[threadIdx.x] = Wl[threadIdx.x]; }
  __syncthreads();
  int i = blockIdx.x * BLK + threadIdx.x;
  float s = 0.f;
  int g = -1;
  if (i < n) {
    float d = dis[i];
    const float4* yp = (const float4*)(y + (size_t)i * 8);
    const float4* ap = (const float4*)(acc + (size_t)i * 8);
    float4 y0 = yp[0], y1v = yp[1], a0 = ap[0], a1 = ap[1];
    float yy[8] = {y0.x,y0.y,y0.z,y0.w, y1v.x,y1v.y,y1v.z,y1v.w};
    float aa[8] = {a0.x,a0.y,a0.z,a0.w, a1.x,a1.y,a1.z,a1.w};
    #pragma unroll
    for (int j = 0; j < 8; ++j) {
      float h = fmaxf(fmaf(d, yy[j] + aa[j], sb[j]), 0.f);
      s = fmaf(h, sw[j], s);
    }
    g = batch[i];
  }
  int g0 = __shfl(g, 0);
  bool uni = __all(g == g0);
  if (uni) {
    #pragma unroll
    for (int off = 32; off > 0; off >>= 1) s += __shfl_down(s, off);
    if ((threadIdx.x & 63) == 0 && g0 >= 0) atomicAdd(&zacc[g0], s);
  } else if (i < n) {
    atomicAdd(&zacc[g], s);
  }
}

// ---------------- out = sigmoid(zacc + bl) ----------------
__global__ void k_out(const float* __restrict__ zacc, const float* __restrict__ bl,
                      float* __restrict__ out, int ng) {
  int i = blockIdx.x * BLK + threadIdx.x;
  if (i < ng) {
    float z = zacc[i] + bl[0];
    float r;
    if (z >= 0.f) { r = 1.f / (1.f + expf(-z)); }
    else          { float e = expf(z); r = e / (1.f + e); }
    out[i] = r;
  }
}

extern "C" void kernel_launch(void* const* d_in, const int* in_sizes, int n_in,
                              void* d_out, int out_size, void* d_ws, size_t ws_size,
                              hipStream_t stream) {
  const float* x   = (const float*)d_in[0];
  const int*   ei  = (const int*)  d_in[1];
  const int*   bat = (const int*)  d_in[2];
  const float* W1  = (const float*)d_in[3];
  const float* b1  = (const float*)d_in[4];
  const float* W2  = (const float*)d_in[5];
  const float* b2  = (const float*)d_in[6];
  const float* Wl  = (const float*)d_in[7];
  const float* bl  = (const float*)d_in[8];
  float* out = (float*)d_out;

  int n  = in_sizes[0] / 16;   // 250000
  int E  = in_sizes[1] / 2;    // 8000000
  int ng = out_size;           // 512

  const int* src = ei;
  const int* dst = ei + E;

  char* wsb = (char*)d_ws;
  size_t offY = (((size_t)n * 4)  + 255) & ~(size_t)255;   // after deg/dis
  size_t offA = offY + ((((size_t)n * 32) + 255) & ~(size_t)255);
  size_t offZ = offA + ((((size_t)n * 32) + 255) & ~(size_t)255);
  int*   deg  = (int*)wsb;
  float* dis  = (float*)wsb;
  float* y    = (float*)(wsb + offY);
  float* acc  = (float*)(wsb + offA);
  float* zacc = (float*)(wsb + offZ);

  int accn = n * 8;
  long long tot = (long long)E * 8;
  int gInit = (accn + BLK - 1) / BLK;
  int gE    = (E + BLK - 1) / BLK;
  int gN    = (n + BLK - 1) / BLK;
  int gS    = (int)((tot + BLK - 1) / BLK);
  int gG    = (ng + BLK - 1) / BLK;

  k_init<<<gInit, BLK, 0, stream>>>(deg, acc, zacc, n, accn, ng);
  k_deg<<<gE, BLK, 0, stream>>>(dst, deg, E);
  k_y1<<<gN, BLK, 0, stream>>>(x, W1, deg, y, n);
  k_scatter<<<gS, BLK, 0, stream>>>(src, dst, y, acc, tot);
  k_mid<<<gN, BLK, 0, stream>>>(dis, y, acc, W2, b1, n);
  k_scatter<<<gS, BLK, 0, stream>>>(src, dst, y, acc, tot);
  k_final<<<gN, BLK, 0, stream>>>(dis, y, acc, b2, Wl, bat, zacc, n);
  k_out<<<gG, BLK, 0, stream>>>(zacc, bl, out, ng);
}